// Round 1
// baseline (877.353 us; speedup 1.0000x reference)
//
#include <hip/hip_runtime.h>

typedef unsigned short ushort_t;
typedef unsigned int uint32;
typedef __attribute__((ext_vector_type(8))) short short8;
typedef __attribute__((ext_vector_type(4))) float f32x4;

#define T_STEPS 256
#define H_DIM 128
#define B_DIM 1024

static __device__ __forceinline__ ushort_t f2bf(float f) {
    uint32 u = __float_as_uint(f);
    u += 0x7FFFu + ((u >> 16) & 1u);
    return (ushort_t)(u >> 16);
}
static __device__ __forceinline__ float sigmoidf_(float x) {
    return 1.0f / (1.0f + __expf(-x));
}
static __device__ __forceinline__ float tanhf_(float x) {
    return 1.0f - 2.0f / (1.0f + __expf(2.0f * x));
}

// ---------------- prep: pack W into MFMA A-fragments, gate-interleaved ----------------
// packed row p = w*32 + tt*16 + m_local; m_local = grp*4 + r  (r = gate i,f,g,o)
// actual W row = r*128 + (w*8 + tt*4 + grp)   [hcol = w*8 + tt*4 + grp]
// A-frag (16x16x32): lane holds A[m = lane&15][k = (lane>>4)*8 + e]
template<int LAYER>
__global__ void prep_frag(const float* __restrict__ Whh, const float* __restrict__ Wih,
                          ushort_t* __restrict__ wfrag) {
    constexpr int KT  = (LAYER == 0) ? 6 : 8;
    constexpr int DIN = (LAYER == 0) ? 64 : 128;
    int i = blockIdx.x * 256 + threadIdx.x;
    int e    = i & 7;
    int lam  = (i >> 3) & 63;
    int rest = i >> 9;
    int kt    = rest % KT;
    int rest2 = rest / KT;
    int tt = rest2 & 1;
    int w  = rest2 >> 1;
    if (w >= 16) return;
    int ml = lam & 15;
    int kg = lam >> 4;
    int k  = kt * 32 + kg * 8 + e;
    int row = (ml & 3) * 128 + w * 8 + tt * 4 + (ml >> 2);
    float v = (k < 128) ? Whh[row * 128 + k] : Wih[row * DIN + (k - 128)];
    wfrag[i] = f2bf(v);
}

__global__ void prep_bias(const float* __restrict__ bih0, const float* __restrict__ bhh0,
                          const float* __restrict__ bih1, const float* __restrict__ bhh1,
                          float* __restrict__ bp0, float* __restrict__ bp1) {
    int i = blockIdx.x * 256 + threadIdx.x;   // 0..1023
    int p = i & 511;
    int w = p >> 5, tt = (p >> 4) & 1, grp = (p >> 2) & 3, r = p & 3;
    int row = r * 128 + w * 8 + tt * 4 + grp;
    if (i < 512) bp0[p] = bih0[row] + bhh0[row];
    else         bp1[p] = bih1[row] + bhh1[row];
}

// ---------------- persistent LSTM layer kernel ----------------
// 64 blocks x 1024 threads (16 waves). Block owns 16 batch rows.
// Wave w owns packed gate rows [w*32, w*32+32) = h-cols [w*8, w*8+8), all 4 gates.
template<int LAYER>
__global__ __launch_bounds__(1024)
void lstm_layer(const float* __restrict__ xin_f32,      // LAYER 0: [B,T,64] f32
                const ushort_t* __restrict__ xin_bf,    // LAYER 1: [B,T,128] bf16
                const ushort_t* __restrict__ wfrag,
                const float* __restrict__ biasp,
                ushort_t* __restrict__ hout,            // LAYER 0 out: [B,T,128] bf16
                float* __restrict__ lastH) {            // LAYER 1 out: [B,128] f32
    constexpr int KT = (LAYER == 0) ? 6 : 8;   // K-tiles of 32 (4 for h, rest for x)
    constexpr int XP = (LAYER == 0) ? 72 : 136; // xbuf row pitch (ushorts), 16B aligned
    __shared__ ushort_t hbuf[2][16][136];
    __shared__ ushort_t xbuf[2][16][XP];

    const int tid  = threadIdx.x;
    const int w    = tid >> 6;
    const int lane = tid & 63;
    const int n    = lane & 15;   // batch col within tile
    const int kg   = lane >> 4;   // k-group / gate-group
    const int b0   = blockIdx.x * 16;

    // weights -> VGPRs (held for entire kernel)
    short8 wf[2][KT];
#pragma unroll
    for (int tt = 0; tt < 2; ++tt)
#pragma unroll
        for (int kt = 0; kt < KT; ++kt)
            wf[tt][kt] = *(const short8*)&wfrag[((((w * 2 + tt) * KT) + kt) * 64 + lane) * 8];

    f32x4 bias[2];
#pragma unroll
    for (int tt = 0; tt < 2; ++tt)
        bias[tt] = *(const f32x4*)&biasp[w * 32 + tt * 16 + kg * 4];

    float cc0 = 0.f, cc1 = 0.f;
    const int hc0 = w * 8 + kg;
    const int hc1 = w * 8 + 4 + kg;

    // h_0 = 0
    for (int i = tid; i < 16 * 136; i += 1024) (&hbuf[0][0][0])[i] = 0;
    // prefill x for t=0 (wave w stages batch row w)
    if (LAYER == 0) {
        float xv = xin_f32[((b0 + w) * T_STEPS + 0) * 64 + lane];
        xbuf[0][w][lane] = f2bf(xv);
    } else {
        uint32 xv = *(const uint32*)&xin_bf[(((b0 + w) * T_STEPS + 0) * 128) + lane * 2];
        *(uint32*)&xbuf[0][w][lane * 2] = xv;
    }
    __syncthreads();

#pragma unroll 1
    for (int t = 0; t < T_STEPS; ++t) {
        const int cur = t & 1, nxt = cur ^ 1;
        const bool pf = (t + 1 < T_STEPS);
        float xf = 0.f; uint32 xu = 0;
        if (pf) {
            if (LAYER == 0) xf = xin_f32[((b0 + w) * T_STEPS + (t + 1)) * 64 + lane];
            else            xu = *(const uint32*)&xin_bf[(((b0 + w) * T_STEPS + (t + 1)) * 128) + lane * 2];
        }

        f32x4 acc0 = {0.f, 0.f, 0.f, 0.f};
        f32x4 acc1 = {0.f, 0.f, 0.f, 0.f};
#pragma unroll
        for (int kt = 0; kt < 4; ++kt) {
            short8 b = *(const short8*)&hbuf[cur][n][kt * 32 + kg * 8];
            acc0 = __builtin_amdgcn_mfma_f32_16x16x32_bf16(wf[0][kt], b, acc0, 0, 0, 0);
            acc1 = __builtin_amdgcn_mfma_f32_16x16x32_bf16(wf[1][kt], b, acc1, 0, 0, 0);
        }
#pragma unroll
        for (int kx = 0; kx < KT - 4; ++kx) {
            short8 b = *(const short8*)&xbuf[cur][n][kx * 32 + kg * 8];
            acc0 = __builtin_amdgcn_mfma_f32_16x16x32_bf16(wf[0][4 + kx], b, acc0, 0, 0, 0);
            acc1 = __builtin_amdgcn_mfma_f32_16x16x32_bf16(wf[1][4 + kx], b, acc1, 0, 0, 0);
        }

        // elementwise update: regs r0..r3 = i,f,g,o for (batch n, hcol)
        float i0 = sigmoidf_(acc0[0] + bias[0][0]);
        float f0 = sigmoidf_(acc0[1] + bias[0][1]);
        float g0 = tanhf_  (acc0[2] + bias[0][2]);
        float o0 = sigmoidf_(acc0[3] + bias[0][3]);
        cc0 = f0 * cc0 + i0 * g0;
        float h0 = o0 * tanhf_(cc0);

        float i1 = sigmoidf_(acc1[0] + bias[1][0]);
        float f1 = sigmoidf_(acc1[1] + bias[1][1]);
        float g1 = tanhf_  (acc1[2] + bias[1][2]);
        float o1 = sigmoidf_(acc1[3] + bias[1][3]);
        cc1 = f1 * cc1 + i1 * g1;
        float h1v = o1 * tanhf_(cc1);

        hbuf[nxt][n][hc0] = f2bf(h0);
        hbuf[nxt][n][hc1] = f2bf(h1v);

        if (LAYER == 1 && t == T_STEPS - 1) {
            lastH[(b0 + n) * 128 + hc0] = h0;
            lastH[(b0 + n) * 128 + hc1] = h1v;
        }
        if (pf) {
            if (LAYER == 0) xbuf[nxt][w][lane] = f2bf(xf);
            else            *(uint32*)&xbuf[nxt][w][lane * 2] = xu;
        }
        __syncthreads();
        if (LAYER == 0) {
            // coalesced bf16 h1 store via LDS: wave w writes batch row w
            uint32 hv = *(const uint32*)&hbuf[nxt][w][lane * 2];
            ((uint32*)hout)[((b0 + w) * T_STEPS + t) * 64 + lane] = hv;
        }
    }
}

// ---------------- head: LayerNorm + fc1(relu) + fc2 ----------------
__global__ __launch_bounds__(256)
void head_kernel(const float* __restrict__ lastH,
                 const float* __restrict__ ln_g, const float* __restrict__ ln_b,
                 const float* __restrict__ fc1w, const float* __restrict__ fc1b,
                 const float* __restrict__ fc2w, const float* __restrict__ fc2b,
                 float* __restrict__ out) {
    __shared__ float ylds[4][128];
    int w = threadIdx.x >> 6, lane = threadIdx.x & 63;
    int row = blockIdx.x * 4 + w;
    float x0 = lastH[row * 128 + lane];
    float x1 = lastH[row * 128 + 64 + lane];
    float s = x0 + x1;
    for (int off = 32; off; off >>= 1) s += __shfl_xor(s, off);
    float mu = s * (1.f / 128.f);
    float d0 = x0 - mu, d1 = x1 - mu;
    float v = d0 * d0 + d1 * d1;
    for (int off = 32; off; off >>= 1) v += __shfl_xor(v, off);
    float rs = rsqrtf(v * (1.f / 128.f) + 1e-5f);
    ylds[w][lane]      = d0 * rs * ln_g[lane]      + ln_b[lane];
    ylds[w][lane + 64] = d1 * rs * ln_g[lane + 64] + ln_b[lane + 64];
    __syncthreads();
    float a = fc1b[lane];
#pragma unroll 4
    for (int k = 0; k < 128; ++k) a += ylds[w][k] * fc1w[lane * 128 + k];
    float r = fmaxf(a, 0.f) * fc2w[lane];
    for (int off = 32; off; off >>= 1) r += __shfl_xor(r, off);
    if (lane == 0) out[row] = r + fc2b[0];
}

extern "C" void kernel_launch(void* const* d_in, const int* in_sizes, int n_in,
                              void* d_out, int out_size, void* d_ws, size_t ws_size,
                              hipStream_t stream) {
    const float* x    = (const float*)d_in[0];
    const float* Wih0 = (const float*)d_in[1];
    const float* Whh0 = (const float*)d_in[2];
    const float* bih0 = (const float*)d_in[3];
    const float* bhh0 = (const float*)d_in[4];
    const float* Wih1 = (const float*)d_in[5];
    const float* Whh1 = (const float*)d_in[6];
    const float* bih1 = (const float*)d_in[7];
    const float* bhh1 = (const float*)d_in[8];
    const float* ln_g = (const float*)d_in[9];
    const float* ln_b = (const float*)d_in[10];
    const float* fc1w = (const float*)d_in[11];
    const float* fc1b = (const float*)d_in[12];
    const float* fc2w = (const float*)d_in[13];
    const float* fc2b = (const float*)d_in[14];

    char* ws = (char*)d_ws;
    ushort_t* h1    = (ushort_t*)(ws);                 // [1024][256][128] bf16 = 64 MiB
    ushort_t* wf0   = (ushort_t*)(ws + 67108864);      // 192 KiB
    ushort_t* wf1   = (ushort_t*)(ws + 67305472);      // 256 KiB
    float*    bp0   = (float*)   (ws + 67567616);      // 2 KiB
    float*    bp1   = (float*)   (ws + 67569664);      // 2 KiB
    float*    lastH = (float*)   (ws + 67571712);      // 512 KiB

    prep_frag<0><<<384, 256, 0, stream>>>(Whh0, Wih0, wf0);
    prep_frag<1><<<512, 256, 0, stream>>>(Whh1, Wih1, wf1);
    prep_bias<<<4, 256, 0, stream>>>(bih0, bhh0, bih1, bhh1, bp0, bp1);

    lstm_layer<0><<<64, 1024, 0, stream>>>(x, nullptr, wf0, bp0, h1, nullptr);
    lstm_layer<1><<<64, 1024, 0, stream>>>(nullptr, h1, wf1, bp1, nullptr, lastH);

    head_kernel<<<256, 256, 0, stream>>>(lastH, ln_g, ln_b, fc1w, fc1b, fc2w, fc2b,
                                         (float*)d_out);
}

// Round 2
// 443.627 us; speedup vs baseline: 1.9777x; 1.9777x over previous
//
#include <hip/hip_runtime.h>

typedef unsigned short ushort_t;
typedef unsigned int uint32;
typedef __attribute__((ext_vector_type(8))) short short8;
typedef __attribute__((ext_vector_type(4))) float f32x4;
typedef __attribute__((ext_vector_type(2))) float f32x2;

#define T_STEPS 256
#define LOG2E   1.4426950408889634f
#define LOG2E2  2.8853900817779268f

static __device__ __forceinline__ ushort_t f2bf(float f) {
    uint32 u = __float_as_uint(f);
    u += 0x7FFFu + ((u >> 16) & 1u);
    return (ushort_t)(u >> 16);
}
static __device__ __forceinline__ float rcp_(float x) { return __builtin_amdgcn_rcpf(x); }
static __device__ __forceinline__ float ex2_(float x) { return __builtin_amdgcn_exp2f(x); }
// sigmoid with pre-scaled arg: x already multiplied by log2e
static __device__ __forceinline__ float sigp_(float x) { return rcp_(1.0f + ex2_(-x)); }

// ---------------- prep: pack W into MFMA A-fragments ----------------
// Tile (w,tt) rows ml=0..15: ml = kg*4 + r ; maps to weight row = r*128 + hc,
// hc = 8w + 2*kg + tt   (so each thread's two outputs are ADJACENT h-columns).
// Rows pre-scaled: log2e for i,f,o ; 2*log2e for g (r==2).
// A-frag (16x16x32): lane holds A[m = lane&15][k = (lane>>4)*8 + e]
template<int LAYER>
__global__ void prep_frag(const float* __restrict__ Whh, const float* __restrict__ Wih,
                          ushort_t* __restrict__ wfrag) {
    constexpr int KT  = (LAYER == 0) ? 6 : 8;
    constexpr int DIN = (LAYER == 0) ? 64 : 128;
    int i = blockIdx.x * 256 + threadIdx.x;
    int e    = i & 7;
    int lam  = (i >> 3) & 63;
    int rest = i >> 9;
    int kt    = rest % KT;
    int rest2 = rest / KT;
    int tt = rest2 & 1;
    int w  = rest2 >> 1;
    if (w >= 16) return;
    int ml = lam & 15;
    int kg = lam >> 4;
    int k  = kt * 32 + kg * 8 + e;
    int r  = ml & 3;
    int hc = 8 * w + 2 * (ml >> 2) + tt;
    int row = r * 128 + hc;
    float scale = (r == 2) ? LOG2E2 : LOG2E;
    float v = (k < 128) ? Whh[row * 128 + k] : Wih[row * DIN + (k - 128)];
    wfrag[i] = f2bf(v * scale);
}

__global__ void prep_bias(const float* __restrict__ bih0, const float* __restrict__ bhh0,
                          const float* __restrict__ bih1, const float* __restrict__ bhh1,
                          float* __restrict__ bp0, float* __restrict__ bp1) {
    int i = blockIdx.x * 256 + threadIdx.x;   // 0..1023
    int p = i & 511;
    int w = p >> 5, tt = (p >> 4) & 1, ml = p & 15;
    int r = ml & 3;
    int hc = 8 * w + 2 * (ml >> 2) + tt;
    int row = r * 128 + hc;
    float scale = (r == 2) ? LOG2E2 : LOG2E;
    if (i < 512) bp0[p] = (bih0[row] + bhh0[row]) * scale;
    else         bp1[p] = (bih1[row] + bhh1[row]) * scale;
}

// ---------------- persistent LSTM layer kernel ----------------
// 64 blocks x 1024 threads (16 waves). Block owns 16 batch rows.
// Wave w owns h-cols [8w, 8w+8): tile tt covers hc = 8w+2kg+tt (thread outputs adjacent).
// LDS feature layout (k-major): feat f of batch n at [f>>5][(f>>3)&3][n][f&7]
//   -> B-frag ds_read_b128 is lane-contiguous (conflict-free);
//   -> h-write is one u32 at w*256 + n*16 + 4*kg (2-way, free).
// Layer0 stores h per step as k-major 4KB records: h1k[(blk*256+t)*4096B + same offset]
// -> Layer1 staging is a straight coalesced u32 copy.
template<int LAYER>
__global__ __launch_bounds__(1024)
void lstm_layer(const float* __restrict__ xin_f32,      // LAYER 0: [B,T,64] f32
                const uint32* __restrict__ xin_rec,     // LAYER 1: k-major records
                const ushort_t* __restrict__ wfrag,
                const float* __restrict__ biasp,
                uint32* __restrict__ hout,              // LAYER 0 out: k-major records
                float* __restrict__ lastH) {            // LAYER 1 out: [B,128] f32
    constexpr int KT = (LAYER == 0) ? 6 : 8;
    constexpr int KX = KT - 4;
    __shared__ ushort_t hb[2][4][4][16][8];             // 8 KiB
    __shared__ ushort_t xb[2][KX][4][16][8];            // 4 or 8 KiB

    const int tid  = threadIdx.x;
    const int w    = tid >> 6;
    const int lane = tid & 63;
    const int n    = lane & 15;   // batch col within tile
    const int kg   = lane >> 4;   // k-group / reg-group
    const int b0   = blockIdx.x * 16;

    // weights -> VGPRs (held entire kernel)
    short8 wf[2][KT];
#pragma unroll
    for (int tt = 0; tt < 2; ++tt)
#pragma unroll
        for (int kt = 0; kt < KT; ++kt)
            wf[tt][kt] = *(const short8*)&wfrag[((((w * 2 + tt) * KT) + kt) * 64 + lane) * 8];

    f32x4 bias0 = *(const f32x4*)&biasp[w * 32 + kg * 4];
    f32x4 bias1 = *(const f32x4*)&biasp[w * 32 + 16 + kg * 4];

    float cc0 = 0.f, cc1 = 0.f;
    const int hc0 = 8 * w + 2 * kg;                     // thread's two h-cols: hc0, hc0+1

    // staging constants
    const int ns  = (tid >> 3) & 15;                    // layer0 staging: batch row
    const int kk  = (tid >> 9) * 32 + ((tid >> 7) & 3) * 8 + (tid & 7);
    const long xbase0 = (long)(b0 + ns) * (T_STEPS * 64) + kk;
    const long rec_base = (long)blockIdx.x * (T_STEPS * 1024);  // u32 units

    // zero h state (buf 0 = 1024 u32)
    ((uint32*)&hb[0][0][0][0][0])[tid] = 0u;
    // prefill x for t=0
    if (LAYER == 0) {
        ((ushort_t*)&xb[0][0][0][0][0])[tid] = f2bf(xin_f32[xbase0]);
    } else {
        ((uint32*)&xb[0][0][0][0][0])[tid] = xin_rec[rec_base + tid];
    }
    __syncthreads();

#define STEP(CUR, NXT, T)                                                          \
    {                                                                              \
        const bool pf = ((T) + 1 < T_STEPS);                                       \
        float xf = 0.f; uint32 xu = 0;                                             \
        if (pf) {                                                                  \
            if (LAYER == 0) xf = xin_f32[xbase0 + ((T) + 1) * 64];                 \
            else            xu = xin_rec[rec_base + ((T) + 1) * 1024 + tid];       \
        }                                                                          \
        f32x4 acc0 = {0.f, 0.f, 0.f, 0.f};                                         \
        f32x4 acc1 = {0.f, 0.f, 0.f, 0.f};                                         \
        _Pragma("unroll")                                                          \
        for (int kt = 0; kt < 4; ++kt) {                                           \
            short8 bfr = *(const short8*)&hb[CUR][kt][kg][n][0];                   \
            acc0 = __builtin_amdgcn_mfma_f32_16x16x32_bf16(wf[0][kt], bfr, acc0, 0, 0, 0); \
            acc1 = __builtin_amdgcn_mfma_f32_16x16x32_bf16(wf[1][kt], bfr, acc1, 0, 0, 0); \
        }                                                                          \
        _Pragma("unroll")                                                          \
        for (int kx = 0; kx < KX; ++kx) {                                          \
            short8 bfr = *(const short8*)&xb[CUR][kx][kg][n][0];                   \
            acc0 = __builtin_amdgcn_mfma_f32_16x16x32_bf16(wf[0][4 + kx], bfr, acc0, 0, 0, 0); \
            acc1 = __builtin_amdgcn_mfma_f32_16x16x32_bf16(wf[1][4 + kx], bfr, acc1, 0, 0, 0); \
        }                                                                          \
        float i0 = sigp_(acc0[0] + bias0[0]);                                      \
        float f0 = sigp_(acc0[1] + bias0[1]);                                      \
        float tg0 = fmaf(2.f, sigp_(acc0[2] + bias0[2]), -1.f);                    \
        float o0 = sigp_(acc0[3] + bias0[3]);                                      \
        cc0 = fmaf(f0, cc0, i0 * tg0);                                             \
        float h0 = o0 * fmaf(2.f, sigp_(cc0 * LOG2E2), -1.f);                      \
        float i1 = sigp_(acc1[0] + bias1[0]);                                      \
        float f1 = sigp_(acc1[1] + bias1[1]);                                      \
        float tg1 = fmaf(2.f, sigp_(acc1[2] + bias1[2]), -1.f);                    \
        float o1 = sigp_(acc1[3] + bias1[3]);                                      \
        cc1 = fmaf(f1, cc1, i1 * tg1);                                             \
        float h1v = o1 * fmaf(2.f, sigp_(cc1 * LOG2E2), -1.f);                     \
        uint32 hp;                                                                 \
        asm("v_cvt_pk_bf16_f32 %0, %1, %2" : "=v"(hp) : "v"(h0), "v"(h1v));        \
        *(uint32*)&hb[NXT][w >> 2][w & 3][n][kg * 2] = hp;                         \
        if (LAYER == 1 && (T) == T_STEPS - 1) {                                    \
            f32x2 hv2 = {h0, h1v};                                                 \
            *(f32x2*)&lastH[(b0 + n) * 128 + hc0] = hv2;                           \
        }                                                                          \
        if (pf) {                                                                  \
            if (LAYER == 0) ((ushort_t*)&xb[NXT][0][0][0][0])[tid] = f2bf(xf);     \
            else            ((uint32*)&xb[NXT][0][0][0][0])[tid] = xu;             \
        }                                                                          \
        if (LAYER == 0)                                                            \
            hout[rec_base + (long)(T) * 1024 + w * 64 + n * 4 + kg] = hp;          \
        __syncthreads();                                                           \
    }

#pragma unroll 1
    for (int t = 0; t < T_STEPS; t += 2) {
        STEP(0, 1, t)
        STEP(1, 0, t + 1)
    }
#undef STEP
}

// ---------------- head: LayerNorm + fc1(relu) + fc2 ----------------
__global__ __launch_bounds__(256)
void head_kernel(const float* __restrict__ lastH,
                 const float* __restrict__ ln_g, const float* __restrict__ ln_b,
                 const float* __restrict__ fc1w, const float* __restrict__ fc1b,
                 const float* __restrict__ fc2w, const float* __restrict__ fc2b,
                 float* __restrict__ out) {
    __shared__ float ylds[4][128];
    int w = threadIdx.x >> 6, lane = threadIdx.x & 63;
    int row = blockIdx.x * 4 + w;
    float x0 = lastH[row * 128 + lane];
    float x1 = lastH[row * 128 + 64 + lane];
    float s = x0 + x1;
    for (int off = 32; off; off >>= 1) s += __shfl_xor(s, off);
    float mu = s * (1.f / 128.f);
    float d0 = x0 - mu, d1 = x1 - mu;
    float v = d0 * d0 + d1 * d1;
    for (int off = 32; off; off >>= 1) v += __shfl_xor(v, off);
    float rs = rsqrtf(v * (1.f / 128.f) + 1e-5f);
    ylds[w][lane]      = d0 * rs * ln_g[lane]      + ln_b[lane];
    ylds[w][lane + 64] = d1 * rs * ln_g[lane + 64] + ln_b[lane + 64];
    __syncthreads();
    float a = fc1b[lane];
#pragma unroll 4
    for (int k = 0; k < 128; ++k) a += ylds[w][k] * fc1w[lane * 128 + k];
    float r = fmaxf(a, 0.f) * fc2w[lane];
    for (int off = 32; off; off >>= 1) r += __shfl_xor(r, off);
    if (lane == 0) out[row] = r + fc2b[0];
}

extern "C" void kernel_launch(void* const* d_in, const int* in_sizes, int n_in,
                              void* d_out, int out_size, void* d_ws, size_t ws_size,
                              hipStream_t stream) {
    const float* x    = (const float*)d_in[0];
    const float* Wih0 = (const float*)d_in[1];
    const float* Whh0 = (const float*)d_in[2];
    const float* bih0 = (const float*)d_in[3];
    const float* bhh0 = (const float*)d_in[4];
    const float* Wih1 = (const float*)d_in[5];
    const float* Whh1 = (const float*)d_in[6];
    const float* bih1 = (const float*)d_in[7];
    const float* bhh1 = (const float*)d_in[8];
    const float* ln_g = (const float*)d_in[9];
    const float* ln_b = (const float*)d_in[10];
    const float* fc1w = (const float*)d_in[11];
    const float* fc1b = (const float*)d_in[12];
    const float* fc2w = (const float*)d_in[13];
    const float* fc2b = (const float*)d_in[14];

    char* ws = (char*)d_ws;
    uint32*   h1k   = (uint32*)  (ws);                 // 64 blk x 256 t x 4 KiB = 64 MiB
    ushort_t* wf0   = (ushort_t*)(ws + 67108864);      // 192 KiB
    ushort_t* wf1   = (ushort_t*)(ws + 67305472);      // 256 KiB
    float*    bp0   = (float*)   (ws + 67567616);      // 2 KiB
    float*    bp1   = (float*)   (ws + 67569664);      // 2 KiB
    float*    lastH = (float*)   (ws + 67571712);      // 512 KiB

    prep_frag<0><<<384, 256, 0, stream>>>(Whh0, Wih0, wf0);
    prep_frag<1><<<512, 256, 0, stream>>>(Whh1, Wih1, wf1);
    prep_bias<<<4, 256, 0, stream>>>(bih0, bhh0, bih1, bhh1, bp0, bp1);

    lstm_layer<0><<<64, 1024, 0, stream>>>(x, nullptr, wf0, bp0, h1k, nullptr);
    lstm_layer<1><<<64, 1024, 0, stream>>>(nullptr, h1k, wf1, bp1, nullptr, lastH);

    head_kernel<<<256, 256, 0, stream>>>(lastH, ln_g, ln_b, fc1w, fc1b, fc2w, fc2b,
                                         (float*)d_out);
}